// Round 10
// baseline (869.588 us; speedup 1.0000x reference)
//
#include <hip/hip_runtime.h>
#include <hip/hip_fp16.h>
#include <math.h>

typedef _Float16 f16x8 __attribute__((ext_vector_type(8)));
typedef float f32x4 __attribute__((ext_vector_type(4)));
typedef unsigned int uint4v __attribute__((ext_vector_type(4)));
typedef unsigned int uint2v __attribute__((ext_vector_type(2)));

#define XSTRIDE 296        // padded LDS row stride (f16 elems)
#define OSTRIDE 292        // padded fp32 out-tile stride (292%32=4 -> 2-way max conflict; mult of 4 for float4 IO)
#define WT_BYTES 720896    // 11*32*32*32 f16 weights in d_ws
// VC coefficient buffer lives at d_ws + WT_BYTES : 11 paths * 32 uints (broadcast-half2)

__device__ __forceinline__ __half2 u2h2(unsigned u){ union{unsigned u; __half2 h;}c; c.u=u; return c.h; }
__device__ __forceinline__ unsigned h22u(__half2 h){ union{__half2 h; unsigned u;}c; c.h=h; return c.u; }

// ---------------- path metadata ----------------
// PATHS = [(0,0,0),(0,1,1),(0,2,2),(1,0,1),(1,1,0),(1,1,2),(1,2,1),(2,0,2),(2,1,1),(2,2,0),(2,2,2)]
__device__ const int g_l[11][3] = {{0,0,0},{0,1,1},{0,2,2},{1,0,1},{1,1,0},{1,1,2},{1,2,1},{2,0,2},{2,1,1},{2,2,0},{2,2,2}};
__device__ const int g_nt[11] = {1,3,5,3,3,11,11,5,11,5,25};
__device__ const signed char g_vi[11][25] = {
  {0},{0,0,0},{0,0,0,0,0},{0,1,2},{0,1,2},
  {0,2,0,1,1,2,2,0,1,0,2},
  {0,2,0,1,1,2,2,0,1,0,2},
  {0,1,2,3,4},
  {0,0,1,1,3,3,4,4,2,2,2},
  {0,1,2,3,4},
  {0,0,2, 1,1,2, 3,3,2, 1,1,4, 3,3,4, 4,4,2, 2, 0,0,1,1,3,3}};
__device__ const signed char g_vj[11][25] = {
  {0},{0,1,2},{0,1,2,3,4},{0,0,0},{0,1,2},
  {2,0,1,0,2,1,2,0,1,0,2},
  {0,0,1,1,3,3,4,4,2,2,2},
  {0,0,0,0,0},
  {0,2,0,1,1,2,2,0,1,0,2},
  {0,1,2,3,4},
  {0,2,0, 1,2,1, 3,2,3, 1,4,1, 3,4,3, 4,2,4, 2, 1,3,0,3,0,1}};
__device__ const signed char g_vk[11][25] = {
  {0},{0,1,2},{0,1,2,3,4},{0,1,2},{0,0,0},
  {0,0,1,1,3,3,4,4,2,2,2},
  {2,0,1,0,2,1,2,0,1,0,2},
  {0,1,2,3,4},
  {2,0,1,0,2,1,2,0,1,0,2},
  {0,0,0,0,0},
  {2,0,0, 2,1,1, 2,3,3, 4,1,1, 4,3,3, 2,4,4, 2, 3,1,3,0,1,0}};

// compile-time structural tables for the fragment build (values come from device solver)
template<int P> struct PD;
template<> struct PD<0>{ enum{D1=1,D2=1,D3=1,OFF1=0,OFF2=0,KB=0,NT=1};
  static constexpr int VI[NT]={0}; static constexpr int VJ[NT]={0}; static constexpr int VK[NT]={0}; };
template<> struct PD<1>{ enum{D1=1,D2=3,D3=3,OFF1=0,OFF2=32,KB=1,NT=3};
  static constexpr int VI[NT]={0,0,0}; static constexpr int VJ[NT]={0,1,2}; static constexpr int VK[NT]={0,1,2}; };
template<> struct PD<2>{ enum{D1=1,D2=5,D3=5,OFF1=0,OFF2=128,KB=4,NT=5};
  static constexpr int VI[NT]={0,0,0,0,0}; static constexpr int VJ[NT]={0,1,2,3,4}; static constexpr int VK[NT]={0,1,2,3,4}; };
template<> struct PD<3>{ enum{D1=3,D2=1,D3=3,OFF1=32,OFF2=0,KB=1,NT=3};
  static constexpr int VI[NT]={0,1,2}; static constexpr int VJ[NT]={0,0,0}; static constexpr int VK[NT]={0,1,2}; };
template<> struct PD<4>{ enum{D1=3,D2=3,D3=1,OFF1=32,OFF2=32,KB=0,NT=3};
  static constexpr int VI[NT]={0,1,2}; static constexpr int VJ[NT]={0,1,2}; static constexpr int VK[NT]={0,0,0}; };
template<> struct PD<5>{ enum{D1=3,D2=3,D3=5,OFF1=32,OFF2=32,KB=4,NT=11};
  static constexpr int VI[NT]={0,2,0,1,1,2,2,0,1,0,2};
  static constexpr int VJ[NT]={2,0,1,0,2,1,2,0,1,0,2};
  static constexpr int VK[NT]={0,0,1,1,3,3,4,4,2,2,2}; };
template<> struct PD<6>{ enum{D1=3,D2=5,D3=3,OFF1=32,OFF2=128,KB=1,NT=11};
  static constexpr int VI[NT]={0,2,0,1,1,2,2,0,1,0,2};
  static constexpr int VJ[NT]={0,0,1,1,3,3,4,4,2,2,2};
  static constexpr int VK[NT]={2,0,1,0,2,1,2,0,1,0,2}; };
template<> struct PD<7>{ enum{D1=5,D2=1,D3=5,OFF1=128,OFF2=0,KB=4,NT=5};
  static constexpr int VI[NT]={0,1,2,3,4}; static constexpr int VJ[NT]={0,0,0,0,0}; static constexpr int VK[NT]={0,1,2,3,4}; };
template<> struct PD<8>{ enum{D1=5,D2=3,D3=3,OFF1=128,OFF2=32,KB=1,NT=11};
  static constexpr int VI[NT]={0,0,1,1,3,3,4,4,2,2,2};
  static constexpr int VJ[NT]={0,2,0,1,1,2,2,0,1,0,2};
  static constexpr int VK[NT]={2,0,1,0,2,1,2,0,1,0,2}; };
template<> struct PD<9>{ enum{D1=5,D2=5,D3=1,OFF1=128,OFF2=128,KB=0,NT=5};
  static constexpr int VI[NT]={0,1,2,3,4}; static constexpr int VJ[NT]={0,1,2,3,4}; static constexpr int VK[NT]={0,0,0,0,0}; };
template<> struct PD<10>{ enum{D1=5,D2=5,D3=5,OFF1=128,OFF2=128,KB=4,NT=25};
  static constexpr int VI[NT]={0,0,2, 1,1,2, 3,3,2, 1,1,4, 3,3,4, 4,4,2, 2, 0,0,1,1,3,3};
  static constexpr int VJ[NT]={0,2,0, 1,2,1, 3,2,3, 1,4,1, 3,4,3, 4,2,4, 2, 1,3,0,3,0,1};
  static constexpr int VK[NT]={2,0,0, 2,1,1, 2,3,3, 4,1,1, 4,3,3, 2,4,4, 2, 3,1,3,0,1,0}; };

union AF { f16x8 s; unsigned int u[4]; };

// first occurrence of this t's VK value? (constant-folds after unroll; lets the
// first term per (k,pr) be a v_pk_mul instead of fma-into-zero)
template<int P>
__device__ __forceinline__ bool firstK(int t){
  #pragma unroll
  for (int s=0;s<t;++s) if (PD<P>::VK[s]==PD<P>::VK[t]) return false;
  return true;
}

// ================= on-device w3j solver (mirrors reference _real_gens + SVD nullspace) =================
__device__ void build_K(int l, double (*K)[5][5])
{
  const int d = 2*l+1;
  double mv[5]; for (int i=0;i<d;++i) mv[i] = (double)(i - l);
  double Lp[5][5] = {};
  for (int i=0;i+1<d;++i) Lp[i+1][i] = sqrt((double)(l*(l+1)) - mv[i]*(mv[i]+1.0));
  double Lr[3][5][5] = {}, Li[3][5][5] = {};
  for (int i=0;i<d;++i) for (int j=0;j<d;++j){
    double lp = Lp[i][j], lm = Lp[j][i];
    Lr[0][i][j] = 0.5*(lp+lm);
    Li[1][i][j] = -0.5*(lp-lm);
    if (i==j) Lr[2][i][j] = mv[i];
  }
  double Qr[5][5] = {}, Qi[5][5] = {};
  Qr[l][l] = 1.0;
  const double s2 = 0.70710678118654752440;
  for (int m=1;m<=l;++m){
    const double sgn = (m&1) ? -1.0 : 1.0;
    Qr[l+m][l-m] = s2;
    Qr[l+m][l+m] = sgn*s2;
    Qi[l-m][l-m] = s2;
    Qi[l-m][l+m] = -sgn*s2;
  }
  for (int a=0;a<3;++a){
    double Tr[5][5], Ti[5][5];
    for (int i=0;i<d;++i) for (int j=0;j<d;++j){
      double tr=0.0, ti=0.0;
      for (int k=0;k<d;++k){
        const double ar=Qr[i][k], ai=Qi[i][k];
        const double br=Li[a][k][j], bi=-Lr[a][k][j];
        tr += ar*br - ai*bi;  ti += ar*bi + ai*br;
      }
      Tr[i][j]=tr; Ti[i][j]=ti;
    }
    for (int i=0;i<d;++i) for (int j=0;j<d;++j){
      double kr=0.0;
      for (int k=0;k<d;++k){
        const double br=Qr[j][k], bi=-Qi[j][k];
        kr += Tr[i][k]*br - Ti[i][k]*bi;
      }
      K[a][i][j] = kr;
    }
  }
}

__device__ __forceinline__ double applyJ(const double (*K1)[5][5], const double (*K2)[5][5],
                                         const double (*K3)[5][5], int a, const double* vec,
                                         int i1,int i2,int i3,int d1,int d2,int d3)
{
  double r = 0.0;
  const int d23 = d2*d3;
  const int b1 = i2*d3 + i3;
  for (int j=0;j<d1;++j) r += K1[a][i1][j]*vec[j*d23 + b1];
  const int b2 = i1*d23 + i3;
  for (int j=0;j<d2;++j) r += K2[a][i2][j]*vec[b2 + j*d3];
  const int b3 = i1*d23 + i2*d3;
  for (int j=0;j<d3;++j) r += K3[a][i3][j]*vec[b3 + j];
  return r;
}

// Fused solver + weight prepack (verified R5/R6). Blocks 0..10 solve; blocks 11..
// prepack weights to f16. vcout stores BROADCAST-HALF2 words.
__global__ void w3j_prepack(const float* __restrict__ w, __half* __restrict__ wt,
                            unsigned* __restrict__ vcout)
{
  if (blockIdx.x >= 11){
    const int o = (blockIdx.x - 11)*384 + threadIdx.x;      // < 360448
    if (o < 11*32*32*32){
      const int j = o & 7, c = (o>>3)&15, q = (o>>7)&3, ni = (o>>9)&1, u = (o>>10)&31, p = o>>15;
      constexpr float A0=0.018042195912175804f, A1=0.027063293868263706f, A2=0.034938562148434216f;
      const float ALPHA[11] = {A0,A1,A2,A1,A0,A2,A1,A2,A1,A0,A2};
      const int vi = q*8 + j;
      const float val = w[((p*32+u)*32 + vi)*32 + ni*16 + c] * ALPHA[p];
      wt[o] = __float2half(val);
    }
    return;
  }

  const int p   = blockIdx.x;
  const int tid = threadIdx.x;        // 384 threads
  const int ax  = tid >> 7;           // axis group 0..2
  const int r   = tid & 127;
  __shared__ double K[3][3][5][5];
  __shared__ double v[128], ju[3][128], jw[3][128], red[128];

  const int l1=g_l[p][0], l2=g_l[p][1], l3=g_l[p][2];
  const int d1=2*l1+1, d2=2*l2+1, d3=2*l3+1, n=d1*d2*d3;
  const int S = l1+l2+l3;

  if (tid==0)   build_K(l1, K[0]);
  if (tid==64)  build_K(l2, K[1]);
  if (tid==128) build_K(l3, K[2]);
  if (tid < 128){
    unsigned h = (unsigned)tid*2654435761u ^ (unsigned)(p*97);
    v[tid] = (tid<n) ? ((double)((h>>9)&0xFFFF)/65536.0 - 0.5) : 0.0;
  }
  __syncthreads();

  int i1=0,i2=0,i3=0;
  if (r<n){ i3 = r % d3; int q = r / d3; i2 = q % d2; i1 = q / d2; }
  const bool act = (r < n);

  // exact spectral projector: prod_{J=S..1}(I - M/(J(J+1))), 3 sweeps
  const int NST = 3*S;
  for (int it=0; it<NST; ++it){
    const int jj = S - (it % S);
    const double invmu = 1.0/(double)(jj*(jj+1));
    if (act) ju[ax][r] = applyJ(K[0],K[1],K[2], ax, v,      i1,i2,i3,d1,d2,d3);
    __syncthreads();
    if (act) jw[ax][r] = applyJ(K[0],K[1],K[2], ax, ju[ax], i1,i2,i3,d1,d2,d3);
    __syncthreads();
    if (act && ax==0) v[r] += (jw[0][r]+jw[1][r]+jw[2][r])*invmu;
    __syncthreads();
  }

  if (tid < 128) red[tid] = (tid<n) ? v[tid]*v[tid] : 0.0;
  __syncthreads();
  for (int s=64;s>0;s>>=1){ if (tid<s) red[tid]+=red[tid+s]; __syncthreads(); }
  if (tid==0){
    const double inv = 1.0/sqrt(red[0]);
    double sgn;
    if (p == 10){
      // (2,2,2): 7-way |max| tie; np's argmax landed on the lone diagonal entry
      // (flat 62) per prior-session absmax evidence. Make C[2,2,2] positive.
      sgn = (v[62] >= 0.0) ? 1.0 : -1.0;
    } else {
      int best=0; long bq=-1;
      for (int i=0;i<n;++i){
        long q = (long)(fabs(v[i])*inv*100000.0 + 0.5);
        if (q > bq){ bq=q; best=i; }
      }
      sgn = (v[best] >= 0.0) ? 1.0 : -1.0;
    }
    const int nt = g_nt[p];
    for (int t=0;t<nt;++t){
      const int flat = ((int)g_vi[p][t]*d2 + (int)g_vj[p][t])*d3 + (int)g_vk[p][t];
      const float cv = (float)(sgn*inv*v[flat]);
      union{__half h; unsigned short s;} c; c.h = __float2half(cv);
      vcout[p*32+t] = ((unsigned)c.s << 16) | (unsigned)c.s;     // broadcast pair
    }
    for (int t=nt;t<32;++t) vcout[p*32+t] = 0u;
  }
}

// ================= main tensor-product kernel =================
// R6 profile: VALUBusy 47.6%, MfmaUtil 23.4%, occ 30.8% (3 w/SIMD), HBM 6.5% ->
// issue/latency-bound. This round: instruction-count reduction.
//  - first-as-mul af build (no zero-inits: every k appears in VK for all paths)
//  - v_perm_b32 for f1 broadcast (1 op) and f2w pack (1 op)
//  - x1 read as ds_read_b64 chunks (4 u per chunk) instead of scalar u16 reads
//    [fix: x1v base includes the Kh*16*D1 halfword offset]
//  - D1==1 paths: g2 = cv*f2 hoisted out of the u-loop (per-u = 4*D3 muls only)
template<int P>
__device__ __forceinline__ void do_path(const unsigned short* __restrict__ X1,
                                        const unsigned short* __restrict__ X2,
                                        const f16x8* __restrict__ WT,
                                        const unsigned* __restrict__ VCH,
                                        int lane, int Kh, int e, int q,
                                        f32x4 (&acc)[2][9])
{
  constexpr int D1=PD<P>::D1, D2=PD<P>::D2, D3=PD<P>::D3, NT=PD<P>::NT, KB=PD<P>::KB;
  // wave-uniform CG coefficients (broadcast-half2) -> scalar regs
  unsigned cvw[NT];
  #pragma unroll
  for (int t=0;t<NT;++t) cvw[t] = VCH[P*32 + t];

  // ---- x2 fragment: f2w[pr][j] = half2{ x2[v'=2pr][j], x2[v'=2pr+1][j] } ----
  unsigned xw[4*D2];
  {
    const uint4v* p2 = (const uint4v*)(X2 + e*XSTRIDE + PD<P>::OFF2 + q*8*D2);
    #pragma unroll
    for (int d=0; d<D2; ++d){
      uint4v wv = p2[d];
      xw[4*d+0]=wv[0]; xw[4*d+1]=wv[1]; xw[4*d+2]=wv[2]; xw[4*d+3]=wv[3];
    }
  }
  unsigned f2w[4][D2];
  #pragma unroll
  for (int pr=0;pr<4;++pr){
    #pragma unroll
    for (int j=0;j<D2;++j){
      const int m0 = 2*pr*D2 + j, m1 = m0 + D2;     // m1 parity = !m0 parity (D2 odd)
      const unsigned sel = (m0&1) ? 0x05040302u : 0x07060100u;
      f2w[pr][j] = __builtin_amdgcn_perm(xw[m1>>1], xw[m0>>1], sel);
    }
  }

  // x1 lane data for THIS wave's K-half: halfwords [Kh*16*D1, Kh*16*D1 + 16*D1)
  // base offset is {32,96,160} bytes for D1={1,3,5} -> 8B alignment preserved
  const uint2v* x1v = (const uint2v*)(X1 + e*XSTRIDE + PD<P>::OFF1 + Kh*16*D1);

  if constexpr (D1 == 1){
    // hoist g2[pr][k] = cv[k]*f2w[pr][VJ[k]] out of the u-loop (VK identity here)
    unsigned g2[4][NT];
    #pragma unroll
    for (int pr=0;pr<4;++pr)
      #pragma unroll
      for (int t=0;t<NT;++t)
        g2[pr][t] = h22u(__hmul2(u2h2(cvw[t]), u2h2(f2w[pr][PD<P>::VJ[t]])));
    for (int ch=0; ch<4; ++ch){
      unsigned xw1[2];
      { uint2v t2 = x1v[ch]; xw1[0]=t2[0]; xw1[1]=t2[1]; }
      #pragma unroll
      for (int uc=0; uc<4; ++uc){
        const int u = Kh*16 + ch*4 + uc;
        f16x8 w0 = WT[((P*32 + u)*2 + 0)*64 + lane];
        f16x8 w1 = WT[((P*32 + u)*2 + 1)*64 + lane];
        const int h = uc;
        const unsigned f1b = __builtin_amdgcn_perm(xw1[h>>1], xw1[h>>1],
                                                   (h&1)?0x03020302u:0x01000100u);
        AF af[D3];
        #pragma unroll
        for (int t=0;t<NT;++t){
          #pragma unroll
          for (int pr=0;pr<4;++pr)
            af[PD<P>::VK[t]].u[pr] = h22u(__hmul2(u2h2(f1b), u2h2(g2[pr][t])));
        }
        #pragma unroll
        for (int k=0;k<D3;++k){
          acc[0][KB+k] = __builtin_amdgcn_mfma_f32_16x16x32_f16(af[k].s, w0, acc[0][KB+k], 0,0,0);
          acc[1][KB+k] = __builtin_amdgcn_mfma_f32_16x16x32_f16(af[k].s, w1, acc[1][KB+k], 0,0,0);
        }
      }
    }
  } else {
    for (int ch=0; ch<4; ++ch){
      unsigned xw1[2*D1];
      #pragma unroll
      for (int d=0; d<D1; ++d){
        uint2v t2 = x1v[ch*D1 + d]; xw1[2*d]=t2[0]; xw1[2*d+1]=t2[1];
      }
      #pragma unroll
      for (int uc=0; uc<4; ++uc){
        const int u = Kh*16 + ch*4 + uc;
        f16x8 w0 = WT[((P*32 + u)*2 + 0)*64 + lane];
        f16x8 w1 = WT[((P*32 + u)*2 + 1)*64 + lane];
        unsigned f1b[D1];
        #pragma unroll
        for (int i=0;i<D1;++i){
          const int h = uc*D1 + i;
          f1b[i] = __builtin_amdgcn_perm(xw1[h>>1], xw1[h>>1],
                                         (h&1)?0x03020302u:0x01000100u);
        }
        AF af[D3];
        #pragma unroll
        for (int t=0;t<NT;++t){
          const __half2 sb = __hmul2(u2h2(cvw[t]), u2h2(f1b[PD<P>::VI[t]]));
          #pragma unroll
          for (int pr=0;pr<4;++pr){
            if (firstK<P>(t))
              af[PD<P>::VK[t]].u[pr] = h22u(__hmul2(sb, u2h2(f2w[pr][PD<P>::VJ[t]])));
            else
              af[PD<P>::VK[t]].u[pr] = h22u(__hfma2(sb, u2h2(f2w[pr][PD<P>::VJ[t]]),
                                                    u2h2(af[PD<P>::VK[t]].u[pr])));
          }
        }
        #pragma unroll
        for (int k=0;k<D3;++k){
          acc[0][KB+k] = __builtin_amdgcn_mfma_f32_16x16x32_f16(af[k].s, w0, acc[0][KB+k], 0,0,0);
          acc[1][KB+k] = __builtin_amdgcn_mfma_f32_16x16x32_f16(af[k].s, w1, acc[1][KB+k], 0,0,0);
        }
      }
    }
  }
}

__global__ __launch_bounds__(256,3) void tp_main(const float* __restrict__ x1g,
                                                 const float* __restrict__ x2g,
                                                 const f16x8* __restrict__ WT,
                                                 const unsigned* __restrict__ VCH,
                                                 float* __restrict__ outg)
{
  __shared__ __align__(16) unsigned short sm[2*32*XSTRIDE];   // 37,888 B
  const int tid = threadIdx.x;
  const int blk = blockIdx.x;
  {
    const float4* g1 = (const float4*)x1g + (size_t)blk*2304;
    const float4* g2 = (const float4*)x2g + (size_t)blk*2304;
    #pragma unroll
    for (int t=0;t<9;++t){
      const int idx = t*256 + tid;            // 0..2303 ; row e = idx/72, col4 = idx%72
      const int e = idx/72, c4 = idx - e*72;
      float4 v1 = g1[idx];
      float4 v2 = g2[idx];
      __half2* d1p = (__half2*)(sm + e*XSTRIDE + c4*4);
      __half2* d2p = (__half2*)(sm + 32*XSTRIDE + e*XSTRIDE + c4*4);
      d1p[0] = __floats2half2_rn(v1.x, v1.y);
      d1p[1] = __floats2half2_rn(v1.z, v1.w);
      d2p[0] = __floats2half2_rn(v2.x, v2.y);
      d2p[1] = __floats2half2_rn(v2.z, v2.w);
    }
  }
  __syncthreads();
  const int lane = tid&63, wv = tid>>6;
  const int mi = wv>>1, Kh = wv&1;            // wave = (m-tile, K-half)
  const int row = lane&15, q = lane>>4;
  const int e = mi*16 + row;
  f32x4 acc[2][9];
  #pragma unroll
  for (int a=0;a<2;++a)
    #pragma unroll
    for (int b=0;b<9;++b){ f32x4 z = {0.f,0.f,0.f,0.f}; acc[a][b] = z; }
  const unsigned short* X1 = sm;
  const unsigned short* X2 = sm + 32*XSTRIDE;
  do_path<0>(X1,X2,WT,VCH,lane,Kh,e,q,acc);
  do_path<1>(X1,X2,WT,VCH,lane,Kh,e,q,acc);
  do_path<2>(X1,X2,WT,VCH,lane,Kh,e,q,acc);
  do_path<3>(X1,X2,WT,VCH,lane,Kh,e,q,acc);
  do_path<4>(X1,X2,WT,VCH,lane,Kh,e,q,acc);
  do_path<5>(X1,X2,WT,VCH,lane,Kh,e,q,acc);
  do_path<6>(X1,X2,WT,VCH,lane,Kh,e,q,acc);
  do_path<7>(X1,X2,WT,VCH,lane,Kh,e,q,acc);
  do_path<8>(X1,X2,WT,VCH,lane,Kh,e,q,acc);
  do_path<9>(X1,X2,WT,VCH,lane,Kh,e,q,acc);
  do_path<10>(X1,X2,WT,VCH,lane,Kh,e,q,acc);
  __syncthreads();                             // all LDS x reads done; re-use LDS as fp32 out tile
  float* O = (float*)sm;                       // 32 rows x OSTRIDE floats = 37,376 B (fits)
  const int erow = mi*16 + q*4;                // D-layout: row = quad*4 + reg
  if (Kh==0){
    #pragma unroll
    for (int ni=0;ni<2;++ni){
      const int w = ni*16 + row;
      #pragma unroll
      for (int kap=0;kap<9;++kap){
        const int col = (kap==0) ? w : (kap<4 ? 32 + w*3 + (kap-1) : 128 + w*5 + (kap-4));
        #pragma unroll
        for (int r=0;r<4;++r) O[(erow+r)*OSTRIDE + col] = acc[ni][kap][r];
      }
    }
  }
  __syncthreads();
  if (Kh==1){
    #pragma unroll
    for (int ni=0;ni<2;++ni){
      const int w = ni*16 + row;
      #pragma unroll
      for (int kap=0;kap<9;++kap){
        const int col = (kap==0) ? w : (kap<4 ? 32 + w*3 + (kap-1) : 128 + w*5 + (kap-4));
        #pragma unroll
        for (int r=0;r<4;++r) O[(erow+r)*OSTRIDE + col] += acc[ni][kap][r];
      }
    }
  }
  __syncthreads();
  float4* o4 = (float4*)outg + (size_t)blk*2304;
  #pragma unroll
  for (int t=0;t<9;++t){
    const int idx = t*256 + tid;               // row = idx/72, c4 = idx%72
    const int r2 = idx/72, c4 = idx - r2*72;
    o4[idx] = *((const float4*)(O + r2*OSTRIDE) + c4);
  }
}

extern "C" void kernel_launch(void* const* d_in, const int* in_sizes, int n_in,
                              void* d_out, int out_size, void* d_ws, size_t ws_size,
                              hipStream_t stream)
{
  const float* x1 = (const float*)d_in[0];
  const float* x2 = (const float*)d_in[1];
  const float* w  = (const float*)d_in[2];
  __half* wt   = (__half*)d_ws;                                  // [0, 720896)
  unsigned* vc = (unsigned*)((char*)d_ws + WT_BYTES);            // 11*32 uints

  const int PB = (11*32*32*32 + 383)/384;       // 939 prepack blocks
  w3j_prepack<<<11 + PB, 384, 0, stream>>>(w, wt, vc);

  const int E  = in_sizes[0] / 288;             // 100,000
  const int nb = E / 32;                        // 3,125
  tp_main<<<nb, 256, 0, stream>>>(x1, x2, (const f16x8*)d_ws, vc, (float*)d_out);
}